// Round 17
// baseline (269.132 us; speedup 1.0000x reference)
//
#include <hip/hip_runtime.h>
#include <math.h>

namespace {
constexpr int BB   = 16;    // batch
constexpr int SS   = 32;    // grid side
constexpr int TT   = 256;   // tiles
constexpr int PP   = 1024;  // patches
constexpr int NTOK = 1025;  // N = R + P
constexpr int KCC  = 256;   // KC
constexpr int KTOK = 257;   // K = R + KC
constexpr int DD   = 768;
constexpr int HH   = 12;
constexpr int DHH  = 64;
constexpr int BNP  = 1040;  // bias n-dim padded (row n = query n; 0 and >=1025 zero)
}

typedef _Float16 f16x8 __attribute__((ext_vector_type(8)));
typedef _Float16 f16x2 __attribute__((ext_vector_type(2)));
typedef float f32x4 __attribute__((ext_vector_type(4)));

#define GLOAD_LDS16(gsrc, ldst)                                               \
  __builtin_amdgcn_global_load_lds(                                           \
      (const __attribute__((address_space(1))) unsigned int*)(gsrc),          \
      (__attribute__((address_space(3))) unsigned int*)(ldst), 16, 0, 0)

// ---------------------------------------------------------------------------
// 0. all three weight tensors -> f16 in one launch
// ---------------------------------------------------------------------------
__global__ __launch_bounds__(256) void cvt_weights_kernel(
    const float* __restrict__ q_w, const float* __restrict__ kv_w,
    const float* __restrict__ out_w,
    _Float16* __restrict__ qwh, _Float16* __restrict__ kvwh,
    _Float16* __restrict__ owh) {
  constexpr int NQ = DD * DD;        // 589824
  constexpr int NK = 2 * DD * DD;    // 1179648
  const int i = (blockIdx.x * 256 + threadIdx.x) * 8;
  const float* src;
  _Float16* dst;
  int off;
  float scale = 1.0f;
  if (i < NQ) { src = q_w; dst = qwh; off = i; scale = 0.125f; }
  else if (i < NQ + NK) { src = kv_w; dst = kvwh; off = i - NQ; }
  else if (i < NQ + NK + NQ) { src = out_w; dst = owh; off = i - NQ - NK; }
  else return;
  const float4 a = *(const float4*)(src + off);
  const float4 b = *(const float4*)(src + off + 4);
  f16x8 o;
  o[0] = (_Float16)(a.x * scale); o[1] = (_Float16)(a.y * scale);
  o[2] = (_Float16)(a.z * scale); o[3] = (_Float16)(a.w * scale);
  o[4] = (_Float16)(b.x * scale); o[5] = (_Float16)(b.y * scale);
  o[6] = (_Float16)(b.z * scale); o[7] = (_Float16)(b.w * scale);
  *(f16x8*)(dst + off) = o;
}

// ---------------------------------------------------------------------------
// 1. tile-context pooling, single pass over x, fused x -> xh conversion
// ---------------------------------------------------------------------------
__global__ __launch_bounds__(256) void ctx_kernel(
    const float* __restrict__ x, const float* __restrict__ logit_w,
    _Float16* __restrict__ ctxh, _Float16* __restrict__ xh) {
  const int blk = blockIdx.x;
  const int b = blk >> 8;
  const int t = blk & 255;
  const int tid = threadIdx.x;
  const int lane = tid & 63;
  const int w = tid >> 6;
  const float* xb = x + (size_t)b * NTOK * DD;
  _Float16* xhb = xh + (size_t)b * NTOK * DD;

  int prow[4];
#pragma unroll
  for (int s = 0; s < 4; ++s)
    prow[s] = 1 + ((t >> 4) * 2 + (s >> 1)) * SS + ((t & 15) * 2 + (s & 1));

  float sv[3][4];
  float part[4] = {0.f, 0.f, 0.f, 0.f};
#pragma unroll
  for (int it = 0; it < 3; ++it) {
    const int d = tid + 256 * it;
    const float lw = logit_w[d];
#pragma unroll
    for (int s = 0; s < 4; ++s) {
      const float xv = xb[(size_t)prow[s] * DD + d];
      sv[it][s] = xv;
      part[s] += xv * lw;
      xhb[(size_t)prow[s] * DD + d] = (_Float16)xv;
    }
  }

#pragma unroll
  for (int dd = 1; dd < 64; dd <<= 1)
#pragma unroll
    for (int s = 0; s < 4; ++s) part[s] += __shfl_xor(part[s], dd, 64);
  __shared__ float wred[4][4];
  if (lane == 0)
#pragma unroll
    for (int s = 0; s < 4; ++s) wred[w][s] = part[s];
  __syncthreads();
  float score[4];
#pragma unroll
  for (int s = 0; s < 4; ++s)
    score[s] = wred[0][s] + wred[1][s] + wred[2][s] + wred[3][s];

  const float mx = fmaxf(fmaxf(score[0], score[1]), fmaxf(score[2], score[3]));
  float e[4], sum = 0.f;
#pragma unroll
  for (int s = 0; s < 4; ++s) { e[s] = expf(score[s] - mx); sum += e[s]; }
  const float inv = 1.f / sum;
#pragma unroll
  for (int s = 0; s < 4; ++s) e[s] *= inv;

  _Float16* crow = ctxh + ((size_t)b * KTOK + 1 + t) * DD;
#pragma unroll
  for (int it = 0; it < 3; ++it) {
    const int d = tid + 256 * it;
    float acc = 0.f;
#pragma unroll
    for (int s = 0; s < 4; ++s) acc += e[s] * sv[it][s];
    crow[d] = (_Float16)acc;
  }
  if (t == 0) {
    _Float16* dst = ctxh + (size_t)b * KTOK * DD;
#pragma unroll
    for (int it = 0; it < 3; ++it) {
      const int d = tid + 256 * it;
      const float xv = xb[d];
      dst[d] = (_Float16)xv;
      xhb[d] = (_Float16)xv;
    }
  }
}

// ---------------------------------------------------------------------------
// 2. pure-f16 MFMA NT GEMM, BK=64, XOR-swizzled LDS, 1-D grid with bijective
//    XCD decode (round 9 -- proven win)
// ---------------------------------------------------------------------------
template <int OUTF16>
__global__ __launch_bounds__(256) void gemm_f16_kernel(
    const _Float16* __restrict__ A, const _Float16* __restrict__ W,
    const float* __restrict__ bias, void* __restrict__ Cout,
    int M, int Nout, int gx) {
  constexpr int BK = 64;
  __shared__ _Float16 As[128 * BK];
  __shared__ _Float16 Ws[128 * BK];

  const int tid = threadIdx.x;
  const int lane = tid & 63;
  const int w = tid >> 6;
  const int fr = lane & 15;
  const int g = lane >> 4;
  const int awm = (w >> 1) * 64;
  const int awn = (w & 1) * 64;

  const int nwg = gridDim.x;
  const int q8 = nwg >> 3, r8 = nwg & 7;
  const int xcd = blockIdx.x & 7;
  const int base = (xcd < r8) ? xcd * (q8 + 1) : r8 * (q8 + 1) + (xcd - r8) * q8;
  const int wg = base + (blockIdx.x >> 3);
  const int row0 = (wg / gx) * 128;
  const int col0 = (wg % gx) * 128;

  const int srow = lane >> 3;                  // 0..7
  const int schunk = (lane & 7) ^ (srow & 7);  // pre-swizzled source chunk

  f32x4 acc[4][4];
#pragma unroll
  for (int i = 0; i < 4; ++i)
#pragma unroll
    for (int j = 0; j < 4; ++j) acc[i][j] = (f32x4){0.f, 0.f, 0.f, 0.f};

  for (int k0 = 0; k0 < 768; k0 += BK) {
    __syncthreads();
#pragma unroll
    for (int c = 0; c < 4; ++c) {
      const int rl = w * 32 + c * 8 + srow;
      int ga = row0 + rl;
      ga = ga < M ? ga : M - 1;
      GLOAD_LDS16(A + (size_t)ga * 768 + k0 + schunk * 8, &As[(w * 32 + c * 8) * BK]);
      GLOAD_LDS16(W + (size_t)(col0 + rl) * 768 + k0 + schunk * 8,
                  &Ws[(w * 32 + c * 8) * BK]);
    }
    __syncthreads();

#pragma unroll
    for (int ks = 0; ks < 2; ++ks) {
      f16x8 af[4], bf[4];
#pragma unroll
      for (int i = 0; i < 4; ++i) {
        const int row = awm + i * 16 + fr;
        af[i] = *(const f16x8*)&As[row * BK + (((ks * 4 + g) ^ (fr & 7)) * 8)];
      }
#pragma unroll
      for (int j = 0; j < 4; ++j) {
        const int row = awn + j * 16 + fr;
        bf[j] = *(const f16x8*)&Ws[row * BK + (((ks * 4 + g) ^ (fr & 7)) * 8)];
      }
#pragma unroll
      for (int i = 0; i < 4; ++i)
#pragma unroll
        for (int j = 0; j < 4; ++j)
          acc[i][j] = __builtin_amdgcn_mfma_f32_16x16x32_f16(af[i], bf[j], acc[i][j], 0, 0, 0);
    }
  }

#pragma unroll
  for (int i = 0; i < 4; ++i) {
    const int rbase = row0 + awm + i * 16 + g * 4;
#pragma unroll
    for (int reg = 0; reg < 4; ++reg) {
      const int gr = rbase + reg;
      if (gr >= M) continue;
      if constexpr (OUTF16) {
        _Float16* crow = (_Float16*)Cout + (size_t)gr * Nout + col0;
#pragma unroll
        for (int j = 0; j < 4; ++j)
          crow[awn + j * 16 + fr] = (_Float16)acc[i][j][reg];
      } else {
        float* crow = (float*)Cout + (size_t)gr * Nout + col0;
#pragma unroll
        for (int j = 0; j < 4; ++j) {
          const int gc = awn + j * 16 + fr;
          crow[gc] = acc[i][j][reg] + bias[col0 + gc];
        }
      }
    }
  }
}

// ---------------------------------------------------------------------------
// 3. CPB bias MLP -> biasK[h][key_c][BNP]
// ---------------------------------------------------------------------------
__global__ __launch_bounds__(256) void cpb_kernel(
    const float* __restrict__ P_pos, const float* __restrict__ tile_centers,
    const float* __restrict__ u_pos,
    const float* __restrict__ w1, const float* __restrict__ b1,
    const float* __restrict__ w2, const float* __restrict__ b2,
    float* __restrict__ biasK) {
  const int idx = blockIdx.x * 256 + threadIdx.x;
  const int c = idx >> 10;
  const int p = idx & 1023;

  const float px = P_pos[p * 3 + 0], py = P_pos[p * 3 + 1], pz = P_pos[p * 3 + 2];
  const float kx = tile_centers[c * 3 + 0] + u_pos[0];
  const float ky = tile_centers[c * 3 + 1] + u_pos[1];
  const float kz = tile_centers[c * 3 + 2] + u_pos[2];
  const float dx = px - kx, dy = py - ky, dz = pz - kz;
  const float fx = copysignf(log1pf(fabsf(dx)), dx);
  const float fy = copysignf(log1pf(fabsf(dy)), dy);
  const float fz = -dz;

  float outh[HH];
#pragma unroll
  for (int h = 0; h < HH; ++h) outh[h] = b2[h];
  for (int j = 0; j < 32; ++j) {
    float hj = fx * w1[j * 3 + 0] + fy * w1[j * 3 + 1] + fz * w1[j * 3 + 2] + b1[j];
    hj = 0.5f * hj * (1.f + erff(hj * 0.70710678118654752f));
#pragma unroll
    for (int h = 0; h < HH; ++h) outh[h] += hj * w2[h * 32 + j];
  }
#pragma unroll
  for (int h = 0; h < HH; ++h) {
    float* row = biasK + ((size_t)h * KCC + c) * BNP;
    row[1 + p] = outh[h];
    if (p == 0) row[0] = 0.f;
    if (p < BNP - 1 - PP) row[1 + PP + p] = 0.f;
  }
}

// ---------------------------------------------------------------------------
// 4. persistent-KV attention, two-pass exact softmax, K-FRAGMENTS IN
//    REGISTERS. __launch_bounds__(512, 2): block is 8 waves = 2/SIMD by
//    construction, so the allocator may use up to 256 VGPRs (R13 failed
//    only because the default cap was 128 -> spill). LDS: V 32K + P 16K.
// ---------------------------------------------------------------------------
__global__ __launch_bounds__(512, 2) void attn_mfma_kernel(
    const _Float16* __restrict__ qf, const _Float16* __restrict__ kvf,
    const float* __restrict__ biasK, _Float16* __restrict__ of) {
  __shared__ _Float16 Vt[4][64 * 64];   // swizzled V^T tiles        (32 KB)
  __shared__ _Float16 Pl[8][16 * 64];   // per-wave P, swizzled      (16 KB)

  const int tid = threadIdx.x;
  const int lane = tid & 63;
  const int w = tid >> 6;
  const int fr = lane & 15;
  const int g = lane >> 4;

  // XCD-affine decode: all of one (b,h) on one block
  const int xcd = blockIdx.x & 7;
  const int grp = xcd + 8 * (blockIdx.x >> 3);  // 0..191
  const int b = grp / HH;
  const int h = grp % HH;

  // ================= stage V (all 512 threads, 2 tiles each) =============
  {
    const int vkp = tid & 31;              // key pair in tile
    const int vdh = ((tid >> 5) & 7) * 8;  // 8 dh rows
    const int kth = tid >> 8;              // 0 or 1
#pragma unroll
    for (int kk = 0; kk < 2; ++kk) {
      const int kt = kth * 2 + kk;
      const int kv0 = kt * 64 + 2 * vkp;
      const f16x8 va = *(const f16x8*)(kvf + ((size_t)b * KTOK + kv0) * (2 * DD) + DD + h * DHH + vdh);
      const f16x8 vbv = *(const f16x8*)(kvf + ((size_t)b * KTOK + kv0 + 1) * (2 * DD) + DD + h * DHH + vdh);
#pragma unroll
      for (int e = 0; e < 8; ++e) {
        const int d = vdh + e;
        f16x2 pr; pr[0] = va[e]; pr[1] = vbv[e];
        *(f16x2*)&Vt[kt][d * 64 + (((vkp >> 2) ^ (d & 7)) * 8) + 2 * (vkp & 3)] = pr;
      }
    }
  }

  // ================= K fragments -> registers (once per wave) ============
  // kf[kt][f][ks] = K[key = kt*64 + f*16 + fr][dh = ks*32 + g*8 .. +8]
  f16x8 kf[4][4][2];
#pragma unroll
  for (int kt = 0; kt < 4; ++kt)
#pragma unroll
    for (int f = 0; f < 4; ++f) {
      const _Float16* srcK =
          kvf + ((size_t)b * KTOK + kt * 64 + f * 16 + fr) * (2 * DD) + h * DHH;
#pragma unroll
      for (int ks = 0; ks < 2; ++ks)
        kf[kt][f][ks] = *(const f16x8*)(srcK + ks * 32 + g * 8);
    }

  // hoisted key-256 fragments
  const _Float16* k256p = kvf + ((size_t)b * KTOK + 256) * (2 * DD) + h * DHH;
  f16x8 kt256[2];
#pragma unroll
  for (int ks = 0; ks < 2; ++ks)
    kt256[ks] = *(const f16x8*)(k256p + ks * 32 + g * 8);
  float v256[4];
#pragma unroll
  for (int j = 0; j < 4; ++j) v256[j] = (float)k256p[DD + j * 16 + fr];

  __syncthreads();  // the ONLY block barrier

  // ================= per-wave query sweep =================
  for (int c = w; c < 65; c += 8) {
    const int qc = c * 16;

    const int qrow = min(qc + fr, NTOK - 1);
    const _Float16* qsrc = qf + ((size_t)b * NTOK + qrow) * DD + h * DHH;
    f16x8 qa[2];
#pragma unroll
    for (int ks = 0; ks < 2; ++ks)
      qa[ks] = *(const f16x8*)(qsrc + ks * 32 + g * 8);

    const int nb = min(qc + g * 4, PP);

    // ---- key-256 dot (VALU, overlaps with QK^T) ----
    float sp = 0.f;
#pragma unroll
    for (int ks = 0; ks < 2; ++ks)
#pragma unroll
      for (int j = 0; j < 8; ++j)
        sp += (float)qa[ks][j] * (float)kt256[ks][j];
    sp += __shfl_xor(sp, 16, 64);
    sp += __shfl_xor(sp, 32, 64);  // lanes sharing fr hold full dot
    const f32x4 bt = *(const f32x4*)&biasK[((size_t)h * KCC + (KCC - 1)) * BNP + nb];

    // ---- pass 1: ALL QK^T (32 MFMA, register operands) + bias ----
    float sm[4][4][4];  // [kt][f][r]
    __builtin_amdgcn_s_setprio(1);
#pragma unroll
    for (int kt = 0; kt < 4; ++kt) {
#pragma unroll
      for (int f = 0; f < 4; ++f) {
        f32x4 sf = (f32x4){0.f, 0.f, 0.f, 0.f};
#pragma unroll
        for (int ks = 0; ks < 2; ++ks)
          sf = __builtin_amdgcn_mfma_f32_16x16x32_f16(qa[ks], kf[kt][f][ks], sf, 0, 0, 0);
        const int key = kt * 64 + f * 16 + fr;
        const int cl = min(max(key - 1, 0), KCC - 1);
        const f32x4 b4 = *(const f32x4*)&biasK[((size_t)h * KCC + cl) * BNP + nb];
        const float bm = (key >= 1) ? 1.f : 0.f;
#pragma unroll
        for (int r = 0; r < 4; ++r) sm[kt][f][r] = sf[r] + bm * b4[r];
      }
    }
    __builtin_amdgcn_s_setprio(0);

    // ---- single exact softmax pass (one reduce, no rescales) ----
    float lr_[4], p256[4];
#pragma unroll
    for (int r = 0; r < 4; ++r) {
      float m01 = fmaxf(sm[0][0][r], sm[0][1][r]);
      float m23 = fmaxf(sm[0][2][r], sm[0][3][r]);
#pragma unroll
      for (int kt = 1; kt < 4; ++kt) {
        m01 = fmaxf(m01, fmaxf(sm[kt][0][r], sm[kt][1][r]));
        m23 = fmaxf(m23, fmaxf(sm[kt][2][r], sm[kt][3][r]));
      }
      float m = fmaxf(m01, m23);
#pragma unroll
      for (int d = 1; d < 16; d <<= 1) m = fmaxf(m, __shfl_xor(m, d, 64));
      const float s256r = __shfl(sp, g * 4 + r, 64) + bt[r];
      m = fmaxf(m, s256r);

      float rs = 0.f;
#pragma unroll
      for (int kt = 0; kt < 4; ++kt)
#pragma unroll
        for (int f = 0; f < 4; ++f) {
          const float pv = __expf(sm[kt][f][r] - m);
          sm[kt][f][r] = pv;
          rs += pv;
        }
#pragma unroll
      for (int d = 1; d < 16; d <<= 1) rs += __shfl_xor(rs, d, 64);
      p256[r] = __expf(s256r - m);
      lr_[r] = rs + p256[r];
    }

    // ---- pass 2: PV per tile (independent, no rescale) ----
    f32x4 outacc[4];
#pragma unroll
    for (int j = 0; j < 4; ++j) outacc[j] = (f32x4){0.f, 0.f, 0.f, 0.f};

#pragma unroll
    for (int kt = 0; kt < 4; ++kt) {
#pragma unroll
      for (int f = 0; f < 4; ++f)
#pragma unroll
        for (int r = 0; r < 4; ++r) {
          const int prw = g * 4 + r;
          Pl[w][prw * 64 + (((2 * f + (fr >> 3)) ^ (prw & 7)) * 8) + (fr & 7)] =
              (_Float16)sm[kt][f][r];
        }
      __builtin_amdgcn_s_setprio(1);
#pragma unroll
      for (int ks = 0; ks < 2; ++ks) {
        const f16x8 pa = *(const f16x8*)&Pl[w][fr * 64 + (((ks * 4 + g) ^ (fr & 7)) * 8)];
#pragma unroll
        for (int j = 0; j < 4; ++j) {
          const f16x8 vbf = *(const f16x8*)&Vt[kt][(j * 16 + fr) * 64 + (((ks * 4 + g) ^ (fr & 7)) * 8)];
          outacc[j] = __builtin_amdgcn_mfma_f32_16x16x32_f16(pa, vbf, outacc[j], 0, 0, 0);
        }
      }
      __builtin_amdgcn_s_setprio(0);
    }

    // ---- epilogue: tail V + normalize + store ----
#pragma unroll
    for (int r = 0; r < 4; ++r) {
      const int n = qc + g * 4 + r;
      if (n >= NTOK) continue;
      const float inv = 1.f / lr_[r];
      _Float16* orow = of + ((size_t)b * NTOK + n) * DD + h * DHH + fr;
#pragma unroll
      for (int j = 0; j < 4; ++j)
        orow[j * 16] = (_Float16)((outacc[j][r] + p256[r] * v256[j]) * inv);
    }
  }
}

// ---------------------------------------------------------------------------
extern "C" void kernel_launch(void* const* d_in, const int* in_sizes, int n_in,
                              void* d_out, int out_size, void* d_ws, size_t ws_size,
                              hipStream_t stream) {
  const float* x            = (const float*)d_in[0];
  const float* logit_w      = (const float*)d_in[1];
  const float* q_w          = (const float*)d_in[2];
  const float* kv_w         = (const float*)d_in[3];
  const float* out_w        = (const float*)d_in[4];
  const float* out_b        = (const float*)d_in[5];
  const float* cpb_w1       = (const float*)d_in[6];
  const float* cpb_b1       = (const float*)d_in[7];
  const float* cpb_w2       = (const float*)d_in[8];
  const float* cpb_b2       = (const float*)d_in[9];
  const float* u_pos        = (const float*)d_in[10];
  const float* P_pos        = (const float*)d_in[11];
  const float* tile_centers = (const float*)d_in[12];
  float* out = (float*)d_out;

  const int Mq  = BB * NTOK;   // 16400
  const int Mkv = BB * KTOK;   // 4112

  char* p = (char*)d_ws;
  auto alloc = [&](size_t bytes) {
    char* r = p;
    p += (bytes + 255) & ~(size_t)255;
    return r;
  };
  _Float16* xh    = (_Float16*)alloc((size_t)Mq * DD * 2);
  _Float16* ctxh  = (_Float16*)alloc((size_t)Mkv * DD * 2);
  _Float16* qwh   = (_Float16*)alloc((size_t)DD * DD * 2);
  _Float16* kvwh  = (_Float16*)alloc((size_t)2 * DD * DD * 2);
  _Float16* owh   = (_Float16*)alloc((size_t)DD * DD * 2);
  _Float16* qbuf  = (_Float16*)alloc((size_t)Mq * DD * 2);
  _Float16* kvbuf = (_Float16*)alloc((size_t)Mkv * 2 * DD * 2);
  float*    biasK = (float*)alloc((size_t)HH * KCC * BNP * 4);
  _Float16* obuf  = (_Float16*)alloc((size_t)Mq * DD * 2);

  const int n_wt = 4 * DD * DD;  // q + kv + out weight elements

  cvt_weights_kernel<<<(n_wt / 8 + 255) / 256, 256, 0, stream>>>(
      q_w, kv_w, out_w, qwh, kvwh, owh);

  ctx_kernel<<<BB * TT, 256, 0, stream>>>(x, logit_w, ctxh, xh);

  const int gq = 6 * 129;    // q / out GEMM: 774 wg
  const int gk = 12 * 33;    // kv GEMM: 396 wg
  gemm_f16_kernel<1><<<gq, 256, 0, stream>>>(xh, qwh, nullptr, qbuf, Mq, DD, 6);
  gemm_f16_kernel<1><<<gk, 256, 0, stream>>>(ctxh, kvwh, nullptr, kvbuf, Mkv, 2 * DD, 12);

  cpb_kernel<<<(PP * KCC) / 256, 256, 0, stream>>>(
      P_pos, tile_centers, u_pos, cpb_w1, cpb_b1, cpb_w2, cpb_b2, biasK);

  attn_mfma_kernel<<<BB * HH, 512, 0, stream>>>(qbuf, kvbuf, biasK, obuf);

  gemm_f16_kernel<0><<<gq, 256, 0, stream>>>(obuf, owh, out_b, out, Mq, DD, 6);
}

// Round 18
// 175.183 us; speedup vs baseline: 1.5363x; 1.5363x over previous
//
#include <hip/hip_runtime.h>
#include <math.h>

namespace {
constexpr int BB   = 16;    // batch
constexpr int SS   = 32;    // grid side
constexpr int TT   = 256;   // tiles
constexpr int PP   = 1024;  // patches
constexpr int NTOK = 1025;  // N = R + P
constexpr int KCC  = 256;   // KC
constexpr int KTOK = 257;   // K = R + KC
constexpr int DD   = 768;
constexpr int HH   = 12;
constexpr int DHH  = 64;
constexpr int BNP  = 1040;  // bias n-dim padded (row n = query n; 0 and >=1025 zero)
}

typedef _Float16 f16x8 __attribute__((ext_vector_type(8)));
typedef _Float16 f16x2 __attribute__((ext_vector_type(2)));
typedef float f32x4 __attribute__((ext_vector_type(4)));

#define GLOAD_LDS16(gsrc, ldst)                                               \
  __builtin_amdgcn_global_load_lds(                                           \
      (const __attribute__((address_space(1))) unsigned int*)(gsrc),          \
      (__attribute__((address_space(3))) unsigned int*)(ldst), 16, 0, 0)

// ---------------------------------------------------------------------------
// 0. all three weight tensors -> f16 in one launch
// ---------------------------------------------------------------------------
__global__ __launch_bounds__(256) void cvt_weights_kernel(
    const float* __restrict__ q_w, const float* __restrict__ kv_w,
    const float* __restrict__ out_w,
    _Float16* __restrict__ qwh, _Float16* __restrict__ kvwh,
    _Float16* __restrict__ owh) {
  constexpr int NQ = DD * DD;        // 589824
  constexpr int NK = 2 * DD * DD;    // 1179648
  const int i = (blockIdx.x * 256 + threadIdx.x) * 8;
  const float* src;
  _Float16* dst;
  int off;
  float scale = 1.0f;
  if (i < NQ) { src = q_w; dst = qwh; off = i; scale = 0.125f; }
  else if (i < NQ + NK) { src = kv_w; dst = kvwh; off = i - NQ; }
  else if (i < NQ + NK + NQ) { src = out_w; dst = owh; off = i - NQ - NK; }
  else return;
  const float4 a = *(const float4*)(src + off);
  const float4 b = *(const float4*)(src + off + 4);
  f16x8 o;
  o[0] = (_Float16)(a.x * scale); o[1] = (_Float16)(a.y * scale);
  o[2] = (_Float16)(a.z * scale); o[3] = (_Float16)(a.w * scale);
  o[4] = (_Float16)(b.x * scale); o[5] = (_Float16)(b.y * scale);
  o[6] = (_Float16)(b.z * scale); o[7] = (_Float16)(b.w * scale);
  *(f16x8*)(dst + off) = o;
}

// ---------------------------------------------------------------------------
// 1. tile-context pooling, single pass over x, fused x -> xh conversion
// ---------------------------------------------------------------------------
__global__ __launch_bounds__(256) void ctx_kernel(
    const float* __restrict__ x, const float* __restrict__ logit_w,
    _Float16* __restrict__ ctxh, _Float16* __restrict__ xh) {
  const int blk = blockIdx.x;
  const int b = blk >> 8;
  const int t = blk & 255;
  const int tid = threadIdx.x;
  const int lane = tid & 63;
  const int w = tid >> 6;
  const float* xb = x + (size_t)b * NTOK * DD;
  _Float16* xhb = xh + (size_t)b * NTOK * DD;

  int prow[4];
#pragma unroll
  for (int s = 0; s < 4; ++s)
    prow[s] = 1 + ((t >> 4) * 2 + (s >> 1)) * SS + ((t & 15) * 2 + (s & 1));

  float sv[3][4];
  float part[4] = {0.f, 0.f, 0.f, 0.f};
#pragma unroll
  for (int it = 0; it < 3; ++it) {
    const int d = tid + 256 * it;
    const float lw = logit_w[d];
#pragma unroll
    for (int s = 0; s < 4; ++s) {
      const float xv = xb[(size_t)prow[s] * DD + d];
      sv[it][s] = xv;
      part[s] += xv * lw;
      xhb[(size_t)prow[s] * DD + d] = (_Float16)xv;
    }
  }

#pragma unroll
  for (int dd = 1; dd < 64; dd <<= 1)
#pragma unroll
    for (int s = 0; s < 4; ++s) part[s] += __shfl_xor(part[s], dd, 64);
  __shared__ float wred[4][4];
  if (lane == 0)
#pragma unroll
    for (int s = 0; s < 4; ++s) wred[w][s] = part[s];
  __syncthreads();
  float score[4];
#pragma unroll
  for (int s = 0; s < 4; ++s)
    score[s] = wred[0][s] + wred[1][s] + wred[2][s] + wred[3][s];

  const float mx = fmaxf(fmaxf(score[0], score[1]), fmaxf(score[2], score[3]));
  float e[4], sum = 0.f;
#pragma unroll
  for (int s = 0; s < 4; ++s) { e[s] = expf(score[s] - mx); sum += e[s]; }
  const float inv = 1.f / sum;
#pragma unroll
  for (int s = 0; s < 4; ++s) e[s] *= inv;

  _Float16* crow = ctxh + ((size_t)b * KTOK + 1 + t) * DD;
#pragma unroll
  for (int it = 0; it < 3; ++it) {
    const int d = tid + 256 * it;
    float acc = 0.f;
#pragma unroll
    for (int s = 0; s < 4; ++s) acc += e[s] * sv[it][s];
    crow[d] = (_Float16)acc;
  }
  if (t == 0) {
    _Float16* dst = ctxh + (size_t)b * KTOK * DD;
#pragma unroll
    for (int it = 0; it < 3; ++it) {
      const int d = tid + 256 * it;
      const float xv = xb[d];
      dst[d] = (_Float16)xv;
      xhb[d] = (_Float16)xv;
    }
  }
}

// ---------------------------------------------------------------------------
// 2. pure-f16 MFMA NT GEMM, BK=64, XOR-swizzled LDS, 1-D grid with bijective
//    XCD decode (round 9 -- proven win)
// ---------------------------------------------------------------------------
template <int OUTF16>
__global__ __launch_bounds__(256) void gemm_f16_kernel(
    const _Float16* __restrict__ A, const _Float16* __restrict__ W,
    const float* __restrict__ bias, void* __restrict__ Cout,
    int M, int Nout, int gx) {
  constexpr int BK = 64;
  __shared__ _Float16 As[128 * BK];
  __shared__ _Float16 Ws[128 * BK];

  const int tid = threadIdx.x;
  const int lane = tid & 63;
  const int w = tid >> 6;
  const int fr = lane & 15;
  const int g = lane >> 4;
  const int awm = (w >> 1) * 64;
  const int awn = (w & 1) * 64;

  const int nwg = gridDim.x;
  const int q8 = nwg >> 3, r8 = nwg & 7;
  const int xcd = blockIdx.x & 7;
  const int base = (xcd < r8) ? xcd * (q8 + 1) : r8 * (q8 + 1) + (xcd - r8) * q8;
  const int wg = base + (blockIdx.x >> 3);
  const int row0 = (wg / gx) * 128;
  const int col0 = (wg % gx) * 128;

  const int srow = lane >> 3;                  // 0..7
  const int schunk = (lane & 7) ^ (srow & 7);  // pre-swizzled source chunk

  f32x4 acc[4][4];
#pragma unroll
  for (int i = 0; i < 4; ++i)
#pragma unroll
    for (int j = 0; j < 4; ++j) acc[i][j] = (f32x4){0.f, 0.f, 0.f, 0.f};

  for (int k0 = 0; k0 < 768; k0 += BK) {
    __syncthreads();
#pragma unroll
    for (int c = 0; c < 4; ++c) {
      const int rl = w * 32 + c * 8 + srow;
      int ga = row0 + rl;
      ga = ga < M ? ga : M - 1;
      GLOAD_LDS16(A + (size_t)ga * 768 + k0 + schunk * 8, &As[(w * 32 + c * 8) * BK]);
      GLOAD_LDS16(W + (size_t)(col0 + rl) * 768 + k0 + schunk * 8,
                  &Ws[(w * 32 + c * 8) * BK]);
    }
    __syncthreads();

#pragma unroll
    for (int ks = 0; ks < 2; ++ks) {
      f16x8 af[4], bf[4];
#pragma unroll
      for (int i = 0; i < 4; ++i) {
        const int row = awm + i * 16 + fr;
        af[i] = *(const f16x8*)&As[row * BK + (((ks * 4 + g) ^ (fr & 7)) * 8)];
      }
#pragma unroll
      for (int j = 0; j < 4; ++j) {
        const int row = awn + j * 16 + fr;
        bf[j] = *(const f16x8*)&Ws[row * BK + (((ks * 4 + g) ^ (fr & 7)) * 8)];
      }
#pragma unroll
      for (int i = 0; i < 4; ++i)
#pragma unroll
        for (int j = 0; j < 4; ++j)
          acc[i][j] = __builtin_amdgcn_mfma_f32_16x16x32_f16(af[i], bf[j], acc[i][j], 0, 0, 0);
    }
  }

#pragma unroll
  for (int i = 0; i < 4; ++i) {
    const int rbase = row0 + awm + i * 16 + g * 4;
#pragma unroll
    for (int reg = 0; reg < 4; ++reg) {
      const int gr = rbase + reg;
      if (gr >= M) continue;
      if constexpr (OUTF16) {
        _Float16* crow = (_Float16*)Cout + (size_t)gr * Nout + col0;
#pragma unroll
        for (int j = 0; j < 4; ++j)
          crow[awn + j * 16 + fr] = (_Float16)acc[i][j][reg];
      } else {
        float* crow = (float*)Cout + (size_t)gr * Nout + col0;
#pragma unroll
        for (int j = 0; j < 4; ++j) {
          const int gc = awn + j * 16 + fr;
          crow[gc] = acc[i][j][reg] + bias[col0 + gc];
        }
      }
    }
  }
}

// ---------------------------------------------------------------------------
// 3. CPB bias MLP -> biasK[h][key_c][BNP]
// ---------------------------------------------------------------------------
__global__ __launch_bounds__(256) void cpb_kernel(
    const float* __restrict__ P_pos, const float* __restrict__ tile_centers,
    const float* __restrict__ u_pos,
    const float* __restrict__ w1, const float* __restrict__ b1,
    const float* __restrict__ w2, const float* __restrict__ b2,
    float* __restrict__ biasK) {
  const int idx = blockIdx.x * 256 + threadIdx.x;
  const int c = idx >> 10;
  const int p = idx & 1023;

  const float px = P_pos[p * 3 + 0], py = P_pos[p * 3 + 1], pz = P_pos[p * 3 + 2];
  const float kx = tile_centers[c * 3 + 0] + u_pos[0];
  const float ky = tile_centers[c * 3 + 1] + u_pos[1];
  const float kz = tile_centers[c * 3 + 2] + u_pos[2];
  const float dx = px - kx, dy = py - ky, dz = pz - kz;
  const float fx = copysignf(log1pf(fabsf(dx)), dx);
  const float fy = copysignf(log1pf(fabsf(dy)), dy);
  const float fz = -dz;

  float outh[HH];
#pragma unroll
  for (int h = 0; h < HH; ++h) outh[h] = b2[h];
  for (int j = 0; j < 32; ++j) {
    float hj = fx * w1[j * 3 + 0] + fy * w1[j * 3 + 1] + fz * w1[j * 3 + 2] + b1[j];
    hj = 0.5f * hj * (1.f + erff(hj * 0.70710678118654752f));
#pragma unroll
    for (int h = 0; h < HH; ++h) outh[h] += hj * w2[h * 32 + j];
  }
#pragma unroll
  for (int h = 0; h < HH; ++h) {
    float* row = biasK + ((size_t)h * KCC + c) * BNP;
    row[1 + p] = outh[h];
    if (p == 0) row[0] = 0.f;
    if (p < BNP - 1 - PP) row[1 + PP + p] = 0.f;
  }
}

// ---------------------------------------------------------------------------
// 4. persistent-KV attention, two-pass exact softmax (round-12 structure,
//    proven 64 us): one block per (b,h), 512 thr = 8 waves, keys 0..255 in
//    64 KB LDS, key 256 register VALU path. 80 KB LDS total.
// ---------------------------------------------------------------------------
__global__ __launch_bounds__(512) void attn_mfma_kernel(
    const _Float16* __restrict__ qf, const _Float16* __restrict__ kvf,
    const float* __restrict__ biasK, _Float16* __restrict__ of) {
  __shared__ _Float16 Kh[4][64 * 64];   // swizzled K tiles, keys 0..255 (32 KB)
  __shared__ _Float16 Vt[4][64 * 64];   // swizzled V^T tiles        (32 KB)
  __shared__ _Float16 Pl[8][16 * 64];   // per-wave P, swizzled      (16 KB)

  const int tid = threadIdx.x;
  const int lane = tid & 63;
  const int w = tid >> 6;
  const int fr = lane & 15;
  const int g = lane >> 4;

  // XCD-affine decode: all of one (b,h) on one block
  const int xcd = blockIdx.x & 7;
  const int grp = xcd + 8 * (blockIdx.x >> 3);  // 0..191
  const int b = grp / HH;
  const int h = grp % HH;

  // ================= stage keys 0..255 once =================
  if (tid < 256) {
    const int ksr = tid >> 2;        // K row 0..63
    const int kc0 = (tid & 3) * 2;   // two 16B chunks
    const int s7 = ksr & 7;
#pragma unroll
    for (int kt = 0; kt < 4; ++kt) {
      const int key = kt * 64 + ksr;  // < 256, valid
      const _Float16* srcK = kvf + ((size_t)b * KTOK + key) * (2 * DD) + h * DHH;
      *(f16x8*)&Kh[kt][ksr * 64 + ((kc0 ^ s7) * 8)] = *(const f16x8*)(srcK + kc0 * 8);
      *(f16x8*)&Kh[kt][ksr * 64 + (((kc0 + 1) ^ s7) * 8)] = *(const f16x8*)(srcK + kc0 * 8 + 8);
    }
  } else {
    const int t2 = tid - 256;
    const int vkp = t2 & 31;         // V key-pair
    const int vdh = (t2 >> 5) * 8;   // V 8 dh rows
#pragma unroll
    for (int kt = 0; kt < 4; ++kt) {
      const int kv0 = kt * 64 + 2 * vkp;
      const f16x8 va = *(const f16x8*)(kvf + ((size_t)b * KTOK + kv0) * (2 * DD) + DD + h * DHH + vdh);
      const f16x8 vbv = *(const f16x8*)(kvf + ((size_t)b * KTOK + kv0 + 1) * (2 * DD) + DD + h * DHH + vdh);
#pragma unroll
      for (int e = 0; e < 8; ++e) {
        const int d = vdh + e;
        f16x2 pr; pr[0] = va[e]; pr[1] = vbv[e];
        *(f16x2*)&Vt[kt][d * 64 + (((vkp >> 2) ^ (d & 7)) * 8) + 2 * (vkp & 3)] = pr;
      }
    }
  }

  // hoisted key-256 fragments (register-resident, loop-invariant)
  const _Float16* k256p = kvf + ((size_t)b * KTOK + 256) * (2 * DD) + h * DHH;
  f16x8 kt256[2];
#pragma unroll
  for (int ks = 0; ks < 2; ++ks)
    kt256[ks] = *(const f16x8*)(k256p + ks * 32 + g * 8);
  float v256[4];
#pragma unroll
  for (int j = 0; j < 4; ++j) v256[j] = (float)k256p[DD + j * 16 + fr];

  __syncthreads();  // the ONLY block barrier

  // ================= per-wave query sweep =================
  for (int c = w; c < 65; c += 8) {
    const int qc = c * 16;

    const int qrow = min(qc + fr, NTOK - 1);
    const _Float16* qsrc = qf + ((size_t)b * NTOK + qrow) * DD + h * DHH;
    f16x8 qa[2];
#pragma unroll
    for (int ks = 0; ks < 2; ++ks)
      qa[ks] = *(const f16x8*)(qsrc + ks * 32 + g * 8);

    const int nb = min(qc + g * 4, PP);

    // ---- key-256 dot (VALU, overlaps with QK^T) ----
    float sp = 0.f;
#pragma unroll
    for (int ks = 0; ks < 2; ++ks)
#pragma unroll
      for (int j = 0; j < 8; ++j)
        sp += (float)qa[ks][j] * (float)kt256[ks][j];
    sp += __shfl_xor(sp, 16, 64);
    sp += __shfl_xor(sp, 32, 64);  // lanes sharing fr hold full dot
    const f32x4 bt = *(const f32x4*)&biasK[((size_t)h * KCC + (KCC - 1)) * BNP + nb];

    // ---- pass 1: ALL QK^T (32 MFMA, independent) + bias ----
    float sm[4][4][4];  // [kt][f][r]
    __builtin_amdgcn_s_setprio(1);
#pragma unroll
    for (int kt = 0; kt < 4; ++kt) {
#pragma unroll
      for (int f = 0; f < 4; ++f) {
        f32x4 sf = (f32x4){0.f, 0.f, 0.f, 0.f};
#pragma unroll
        for (int ks = 0; ks < 2; ++ks) {
          const f16x8 kf = *(const f16x8*)&Kh[kt][(f * 16 + fr) * 64 + (((ks * 4 + g) ^ (fr & 7)) * 8)];
          sf = __builtin_amdgcn_mfma_f32_16x16x32_f16(qa[ks], kf, sf, 0, 0, 0);
        }
        const int key = kt * 64 + f * 16 + fr;
        const int cl = min(max(key - 1, 0), KCC - 1);
        const f32x4 b4 = *(const f32x4*)&biasK[((size_t)h * KCC + cl) * BNP + nb];
        const float bm = (key >= 1) ? 1.f : 0.f;
#pragma unroll
        for (int r = 0; r < 4; ++r) sm[kt][f][r] = sf[r] + bm * b4[r];
      }
    }
    __builtin_amdgcn_s_setprio(0);

    // ---- single exact softmax pass (one reduce, no rescales) ----
    float lr_[4], p256[4];
#pragma unroll
    for (int r = 0; r < 4; ++r) {
      float m01 = fmaxf(sm[0][0][r], sm[0][1][r]);
      float m23 = fmaxf(sm[0][2][r], sm[0][3][r]);
#pragma unroll
      for (int kt = 1; kt < 4; ++kt) {
        m01 = fmaxf(m01, fmaxf(sm[kt][0][r], sm[kt][1][r]));
        m23 = fmaxf(m23, fmaxf(sm[kt][2][r], sm[kt][3][r]));
      }
      float m = fmaxf(m01, m23);
#pragma unroll
      for (int d = 1; d < 16; d <<= 1) m = fmaxf(m, __shfl_xor(m, d, 64));
      const float s256r = __shfl(sp, g * 4 + r, 64) + bt[r];
      m = fmaxf(m, s256r);

      float rs = 0.f;
#pragma unroll
      for (int kt = 0; kt < 4; ++kt)
#pragma unroll
        for (int f = 0; f < 4; ++f) {
          const float pv = __expf(sm[kt][f][r] - m);
          sm[kt][f][r] = pv;
          rs += pv;
        }
#pragma unroll
      for (int d = 1; d < 16; d <<= 1) rs += __shfl_xor(rs, d, 64);
      p256[r] = __expf(s256r - m);
      lr_[r] = rs + p256[r];
    }

    // ---- pass 2: PV per tile (independent, no rescale) ----
    f32x4 outacc[4];
#pragma unroll
    for (int j = 0; j < 4; ++j) outacc[j] = (f32x4){0.f, 0.f, 0.f, 0.f};

#pragma unroll
    for (int kt = 0; kt < 4; ++kt) {
#pragma unroll
      for (int f = 0; f < 4; ++f)
#pragma unroll
        for (int r = 0; r < 4; ++r) {
          const int prw = g * 4 + r;
          Pl[w][prw * 64 + (((2 * f + (fr >> 3)) ^ (prw & 7)) * 8) + (fr & 7)] =
              (_Float16)sm[kt][f][r];
        }
      __builtin_amdgcn_s_setprio(1);
#pragma unroll
      for (int ks = 0; ks < 2; ++ks) {
        const f16x8 pa = *(const f16x8*)&Pl[w][fr * 64 + (((ks * 4 + g) ^ (fr & 7)) * 8)];
#pragma unroll
        for (int j = 0; j < 4; ++j) {
          const f16x8 vbf = *(const f16x8*)&Vt[kt][(j * 16 + fr) * 64 + (((ks * 4 + g) ^ (fr & 7)) * 8)];
          outacc[j] = __builtin_amdgcn_mfma_f32_16x16x32_f16(pa, vbf, outacc[j], 0, 0, 0);
        }
      }
      __builtin_amdgcn_s_setprio(0);
    }

    // ---- epilogue: tail V + normalize + store ----
#pragma unroll
    for (int r = 0; r < 4; ++r) {
      const int n = qc + g * 4 + r;
      if (n >= NTOK) continue;
      const float inv = 1.f / lr_[r];
      _Float16* orow = of + ((size_t)b * NTOK + n) * DD + h * DHH + fr;
#pragma unroll
      for (int j = 0; j < 4; ++j)
        orow[j * 16] = (_Float16)((outacc[j][r] + p256[r] * v256[j]) * inv);
    }
  }
}

// ---------------------------------------------------------------------------
extern "C" void kernel_launch(void* const* d_in, const int* in_sizes, int n_in,
                              void* d_out, int out_size, void* d_ws, size_t ws_size,
                              hipStream_t stream) {
  const float* x            = (const float*)d_in[0];
  const float* logit_w      = (const float*)d_in[1];
  const float* q_w          = (const float*)d_in[2];
  const float* kv_w         = (const float*)d_in[3];
  const float* out_w        = (const float*)d_in[4];
  const float* out_b        = (const float*)d_in[5];
  const float* cpb_w1       = (const float*)d_in[6];
  const float* cpb_b1       = (const float*)d_in[7];
  const float* cpb_w2       = (const float*)d_in[8];
  const float* cpb_b2       = (const float*)d_in[9];
  const float* u_pos        = (const float*)d_in[10];
  const float* P_pos        = (const float*)d_in[11];
  const float* tile_centers = (const float*)d_in[12];
  float* out = (float*)d_out;

  const int Mq  = BB * NTOK;   // 16400
  const int Mkv = BB * KTOK;   // 4112

  char* p = (char*)d_ws;
  auto alloc = [&](size_t bytes) {
    char* r = p;
    p += (bytes + 255) & ~(size_t)255;
    return r;
  };
  _Float16* xh    = (_Float16*)alloc((size_t)Mq * DD * 2);
  _Float16* ctxh  = (_Float16*)alloc((size_t)Mkv * DD * 2);
  _Float16* qwh   = (_Float16*)alloc((size_t)DD * DD * 2);
  _Float16* kvwh  = (_Float16*)alloc((size_t)2 * DD * DD * 2);
  _Float16* owh   = (_Float16*)alloc((size_t)DD * DD * 2);
  _Float16* qbuf  = (_Float16*)alloc((size_t)Mq * DD * 2);
  _Float16* kvbuf = (_Float16*)alloc((size_t)Mkv * 2 * DD * 2);
  float*    biasK = (float*)alloc((size_t)HH * KCC * BNP * 4);
  _Float16* obuf  = (_Float16*)alloc((size_t)Mq * DD * 2);

  const int n_wt = 4 * DD * DD;  // q + kv + out weight elements

  cvt_weights_kernel<<<(n_wt / 8 + 255) / 256, 256, 0, stream>>>(
      q_w, kv_w, out_w, qwh, kvwh, owh);

  ctx_kernel<<<BB * TT, 256, 0, stream>>>(x, logit_w, ctxh, xh);

  const int gq = 6 * 129;    // q / out GEMM: 774 wg
  const int gk = 12 * 33;    // kv GEMM: 396 wg
  gemm_f16_kernel<1><<<gq, 256, 0, stream>>>(xh, qwh, nullptr, qbuf, Mq, DD, 6);
  gemm_f16_kernel<1><<<gk, 256, 0, stream>>>(ctxh, kvwh, nullptr, kvbuf, Mkv, 2 * DD, 12);

  cpb_kernel<<<(PP * KCC) / 256, 256, 0, stream>>>(
      P_pos, tile_centers, u_pos, cpb_w1, cpb_b1, cpb_w2, cpb_b2, biasK);

  attn_mfma_kernel<<<BB * HH, 512, 0, stream>>>(qbuf, kvbuf, biasK, obuf);

  gemm_f16_kernel<0><<<gq, 256, 0, stream>>>(obuf, owh, out_b, out, Mq, DD, 6);
}